// Round 11
// baseline (211.855 us; speedup 1.0000x reference)
//
#include <hip/hip_runtime.h>

#define N_ANCHORS 5000
#define N_CLASSES 80
#define OUT_COLS  84
#define MAX_BOXES 300
#define SCORE_THR 0.05f

#define SORT_PAD  5056
#define NB        4096
#define BLOCK     1024
#define SLOTS     16                 // ring slots (KS/KSA/Iring/flags)
#define DONEP     0x40000000

typedef unsigned long long u64;
typedef unsigned int u32;

#define WG __HIP_MEMORY_SCOPE_WORKGROUP

__device__ __forceinline__ float readlane_f(float v, int l) {
    return __int_as_float(__builtin_amdgcn_readlane(__float_as_int(v), l));
}
__device__ __forceinline__ u32 aload(u32* p) {
    return __hip_atomic_load(p, __ATOMIC_ACQUIRE, WG);
}
// monotone score->bucket map (load balance only, never exactness)
__device__ __forceinline__ int bucket_of(float s) {
    float u = sqrtf(s);
    int b = (int)((u - 0.2236f) * 5275.0f);
    return min(max(b, 0), NB - 1);
}
// IoU(a,b) > 0.5  <=>  3*inter > areaA+areaB  (union>0: areas >= 1)
__device__ __forceinline__ bool iou_gt(float4 a, float aa, float4 b, float ab) {
    float iw = fmaxf(fminf(a.z, b.z) - fmaxf(a.x, b.x), 0.0f);
    float ih = fmaxf(fminf(a.w, b.w) - fmaxf(a.y, b.y), 0.0f);
    return 3.0f * (iw * ih) > aa + ab;
}

// ================= 1) prep: coalesced out init + cls transpose =================
#define INIT_BLKS 1641               // ceil(5000*84/256)
#define TR_BX     157
#define TR_BY     3
#define TR_BLKS   (TR_BX * TR_BY)

__global__ __launch_bounds__(256) void prep(const float* __restrict__ boxes,
                                            const float* __restrict__ cls,
                                            float* __restrict__ clsT,
                                            float* __restrict__ out) {
    __shared__ float tile[32][33];
    int b = blockIdx.x;
    if (b < INIT_BLKS) {
        int i = b * 256 + threadIdx.x;
        if (i < N_ANCHORS * OUT_COLS) {
            int row = i / OUT_COLS, col = i - row * OUT_COLS;
            out[i] = (col < 4) ? boxes[row * 4 + col] : 0.0f;
        }
        return;
    }
    b -= INIT_BLKS;
    int bx_ = b % TR_BX, by_ = b / TR_BX;
    int j0 = bx_ * 32, c0 = by_ * 32;
    int tx = threadIdx.x & 31, ty = threadIdx.x >> 5;
    #pragma unroll
    for (int r = 0; r < 32; r += 8) {
        int j = j0 + ty + r, c = c0 + tx;
        tile[ty + r][tx] = (j < N_ANCHORS && c < N_CLASSES) ? cls[j * N_CLASSES + c] : 0.0f;
    }
    __syncthreads();
    #pragma unroll
    for (int r = 0; r < 32; r += 8) {
        int c = c0 + ty + r, j = j0 + tx;
        if (c < N_CLASSES && j < N_ANCHORS) clsT[(size_t)c * N_ANCHORS + j] = tile[tx][ty + r];
    }
}

// ================= 2) per-class: LDS sort + pipelined mask-free scan =================
__global__ __launch_bounds__(BLOCK, 1) void nms(const float* __restrict__ clsT,
                                                const float4* __restrict__ boxes4,
                                                float* __restrict__ out) {
    __shared__ u64 lk[SORT_PAD];        // 40448 B sorted keys (score desc, idx asc)
    __shared__ u32 hist[NB];            // 16384 B; aliased by Iring after sort
    __shared__ float4 kbox[MAX_BOXES + 8];
    __shared__ u64 KS[SLOTS], KSA[SLOTS];
    __shared__ u32 flagI[SLOTS], flagK[SLOTS], flagKA[SLOTS], KBa[SLOTS];
    __shared__ u32 wtot[16];
    __shared__ u32 prog, kcnt;
    u64* Iring = (u64*)hist;            // SLOTS*64*8 = 8192 <= 16384

    const int c = blockIdx.x;
    const int t = threadIdx.x;
    const int lane = t & 63;
    const int wv = t >> 6;

    // ---------- sort phase (all 16 waves) ----------
    const float4* cp4 = (const float4*)(clsT + (size_t)c * N_ANCHORS);
    u32 sb[8];
    #pragma unroll
    for (int m = 0; m < 2; ++m) {
        int vi = m * 1024 + t;
        float4 v = make_float4(0.f, 0.f, 0.f, 0.f);
        if (vi < N_ANCHORS / 4) v = cp4[vi];
        sb[m * 4 + 0] = (v.x > SCORE_THR) ? __float_as_uint(v.x) : 0u;
        sb[m * 4 + 1] = (v.y > SCORE_THR) ? __float_as_uint(v.y) : 0u;
        sb[m * 4 + 2] = (v.z > SCORE_THR) ? __float_as_uint(v.z) : 0u;
        sb[m * 4 + 3] = (v.w > SCORE_THR) ? __float_as_uint(v.w) : 0u;
    }
    for (int b = t; b < NB; b += BLOCK) hist[b] = 0u;
    if (t < SLOTS) { flagI[t] = 0u; flagK[t] = 0u; flagKA[t] = 0u; }
    if (t == 0) { prog = 0u; kcnt = 0u; }
    __syncthreads();
    #pragma unroll
    for (int m = 0; m < 8; ++m)
        if (sb[m]) atomicAdd(&hist[bucket_of(__uint_as_float(sb[m]))], 1u);
    __syncthreads();

    const int hbase = t * 4;
    u32 vals[4]; u32 run = 0;
    #pragma unroll
    for (int k = 0; k < 4; ++k) { run += hist[hbase + k]; vals[k] = run; }
    u32 x = run;
    #pragma unroll
    for (int off = 1; off < 64; off <<= 1) { u32 y = __shfl_up(x, off); if (lane >= off) x += y; }
    if (lane == 63) wtot[wv] = x;
    __syncthreads();
    u32 woff = 0;
    for (int w = 0; w < wv; ++w) woff += wtot[w];
    const u32 exb = woff + x - run;
    #pragma unroll
    for (int k = 0; k < 4; ++k) hist[hbase + k] = exb + (k ? vals[k - 1] : 0u);
    __syncthreads();
    #pragma unroll
    for (int m = 0; m < 8; ++m) {
        if (sb[m]) {
            int j = ((m >> 2) * 1024 + t) * 4 + (m & 3);
            u32 pos = atomicAdd(&hist[bucket_of(__uint_as_float(sb[m]))], 1u);
            lk[pos] = ((u64)sb[m] << 32) | (u32)(~(u32)j);
        }
    }
    __syncthreads();
    const int total = (int)hist[NB - 1];
    for (int v = total + t; v < SORT_PAD; v += BLOCK) lk[v] = 0ull;
    for (int b = hbase; b < hbase + 4; ++b) {
        int s0 = b ? (int)hist[b - 1] : 0;
        int e  = (int)hist[b];
        for (int i = s0 + 1; i < e; ++i) {
            u64 key = lk[i]; int q = i - 1;
            while (q >= s0 && lk[q] < key) { lk[q + 1] = lk[q]; --q; }
            lk[q + 1] = key;
        }
    }
    __syncthreads();                    // LAST barrier; roles diverge
    const int nch = (total + 63) >> 6;

    if (wv == 1 || wv == 2) {
        // ======= intra workers: columns only over alive-superset (from KSA) =======
        for (int j = wv - 1; j < nch; j += 2) {
            const int slot = j & (SLOTS - 1);
            u32 p;
            for (;;) {
                p = aload(&prog);
                if ((int)p >= j - 8) break;
                __builtin_amdgcn_s_sleep(4);
            }
            if (p >= DONEP) return;
            u64 e = lk[j * 64 + lane];
            u32 jj = e ? ~(u32)e : 0u;
            float4 bx = boxes4[jj];                      // gather early (latency slack)
            float ar = (bx.z - bx.x) * (bx.w - bx.y);
            for (;;) {
                u32 f = aload(&flagKA[slot]);
                if (f == (u32)(j + 1)) break;
                if (aload(&prog) >= DONEP) return;
                __builtin_amdgcn_s_sleep(1);
            }
            u64 S = ~KSA[slot];                          // alive superset positions
            u64 word = 0ull, mset = S;
            while (mset) {
                int q = __ffsll((long long)mset) - 1;
                mset &= mset - 1;
                float4 o;
                o.x = readlane_f(bx.x, q); o.y = readlane_f(bx.y, q);
                o.z = readlane_f(bx.z, q); o.w = readlane_f(bx.w, q);
                float ao = (o.z - o.x) * (o.w - o.y);
                if (iou_gt(bx, ar, o, ao)) word |= (1ull << q);
            }
            Iring[slot * 64 + lane] = word;
            if (lane == 0)
                __hip_atomic_store(&flagI[slot], (u32)(j + 1), __ATOMIC_RELEASE, WG);
        }
        return;
    }
    if (wv >= 3) {
        // ======= sweep workers: suppressed-by-kept, two-stage + early exit =======
        for (int j = wv - 3; j < nch; j += 13) {
            const int slot = j & (SLOTS - 1);
            u32 p;
            for (;;) {                                  // stage A gate
                p = aload(&prog);
                if ((int)p >= j - 10) break;
                __builtin_amdgcn_s_sleep(4);
            }
            if (p >= DONEP) return;
            u64 e = lk[j * 64 + lane];
            bool validL = (e != 0ull);
            u32 jj = validL ? ~(u32)e : 0u;
            float4 bx = boxes4[jj];
            float ar = (bx.z - bx.x) * (bx.w - bx.y);
            bool sup = !validL;                          // padding counts as dead
            u32 ka = aload(&kcnt);
            u64 livem = __ballot(!sup);
            for (u32 r = 0; r < ka && livem; ++r) {
                float4 q = kbox[r];
                float aq = (q.z - q.x) * (q.w - q.y);
                if (!sup && iou_gt(bx, ar, q, aq)) sup = true;
                if ((r & 7u) == 7u) livem = __ballot(!sup);
            }
            u64 ksa = __ballot(sup);
            if (lane == 0) {
                KSA[slot] = ksa;
                __hip_atomic_store(&flagKA[slot], (u32)(j + 1), __ATOMIC_RELEASE, WG);
            }
            for (;;) {                                  // stage B gate
                p = aload(&prog);
                if ((int)p >= j - 2) break;
                __builtin_amdgcn_s_sleep(1);
            }
            u32 kb2 = (p >= DONEP) ? ka : aload(&kcnt);
            if (kb2 < ka) kb2 = ka;
            u64 livem2 = __ballot(!sup);
            for (u32 r = ka; r < kb2 && livem2; ++r) {
                float4 q = kbox[r];
                float aq = (q.z - q.x) * (q.w - q.y);
                if (!sup && iou_gt(bx, ar, q, aq)) sup = true;
                if ((r & 7u) == 7u) livem2 = __ballot(!sup);
            }
            u64 ks = __ballot(sup);
            if (lane == 0) {
                KS[slot] = ks; KBa[slot] = kb2;
                __hip_atomic_store(&flagK[slot], (u32)(j + 1), __ATOMIC_RELEASE, WG);
            }
            if (p >= DONEP) return;
        }
        return;
    }

    // ======= wave 0: serial scan =======
    int kept = 0; u32 kcur = 0; bool capped = false;
    u64 key = (nch > 0) ? lk[lane] : 0ull;
    float4 bx = boxes4[key ? ~(u32)key : 0u];
    for (int k = 0; k < nch; ++k) {
        const int slot = k & (SLOTS - 1);
        // prefetch next chunk (independent of this chunk's outcome)
        u64 keyN = 0ull; float4 bxN = bx;
        if (k + 1 < nch) {
            keyN = lk[(k + 1) * 64 + lane];
            bxN = boxes4[keyN ? ~(u32)keyN : 0u];
        }
        bool valid = (key != 0ull);
        u32 j = valid ? ~(u32)key : 0u;
        float sc = __uint_as_float((u32)(key >> 32));

        while (aload(&flagK[slot]) != (u32)(k + 1)) { }   // tight spin
        u64 ks = KS[slot];
        if (ks != ~0ull) {                                // fast-skip fully-dead chunks
            u32 kb = KBa[slot];
            float ar = (bx.z - bx.x) * (bx.w - bx.y);
            bool alive = valid && !((ks >> lane) & 1ull);
            for (u32 r = kb; r < kcur; ++r) {             // top-up: recent keeps
                float4 q = kbox[r];
                float aq = (q.z - q.x) * (q.w - q.y);
                if (alive && iou_gt(bx, ar, q, aq)) alive = false;
            }
            u64 rem = __ballot(alive);
            if (rem) {
                while (aload(&flagI[slot]) != (u32)(k + 1)) { }
                u64 I = Iring[slot * 64 + lane];
                u64 km = 0ull;
                while (rem) {                             // SALU keep chain
                    int pos = __ffsll((long long)rem) - 1;
                    km |= 1ull << pos;
                    if (++kept == MAX_BOXES) { capped = true; break; }
                    u32 lo = (u32)__builtin_amdgcn_readlane((int)(u32)I, pos);
                    u32 hi = (u32)__builtin_amdgcn_readlane((int)(u32)(I >> 32), pos);
                    rem &= ~(((u64)hi << 32) | (u64)lo);  // diag bit kills pos itself
                }
                if ((km >> lane) & 1ull) {
                    out[(size_t)j * OUT_COLS + 4 + c] = sc;
                    kbox[kcur + __popcll(km & ((1ull << lane) - 1ull))] = bx;
                }
                kcur += (u32)__popcll(km);
            }
        }
        if (capped) break;
        if (lane == 0) {
            __hip_atomic_store(&kcnt, kcur, __ATOMIC_RELAXED, WG);
            __hip_atomic_store(&prog, (u32)(k + 1), __ATOMIC_RELEASE, WG);
        }
        key = keyN; bx = bxN;
    }
    if (lane == 0) __hip_atomic_store(&prog, (u32)DONEP, __ATOMIC_RELEASE, WG);
}

extern "C" void kernel_launch(void* const* d_in, const int* in_sizes, int n_in,
                              void* d_out, int out_size, void* d_ws, size_t ws_size,
                              hipStream_t stream) {
    const float* boxes = (const float*)d_in[0];
    const float* cls   = (const float*)d_in[1];
    float* out = (float*)d_out;
    float* clsT = (float*)d_ws;                    // 1.60 MB scratch

    prep<<<INIT_BLKS + TR_BLKS, 256, 0, stream>>>(boxes, cls, clsT, out);
    nms<<<N_CLASSES, BLOCK, 0, stream>>>(clsT, (const float4*)boxes, out);
}

// Round 12
// 210.009 us; speedup vs baseline: 1.0088x; 1.0088x over previous
//
#include <hip/hip_runtime.h>

#define N_ANCHORS 5000
#define N_CLASSES 80
#define OUT_COLS  84
#define MAX_BOXES 300
#define SCORE_THR 0.05f

#define SORT_PAD  5056
#define NB        4096
#define BLOCK     1024
#define SLOTS     8
#define DONEP     0x40000000

typedef unsigned long long u64;
typedef unsigned int u32;

#define WG __HIP_MEMORY_SCOPE_WORKGROUP

__device__ __forceinline__ float readlane_f(float v, int l) {
    return __int_as_float(__builtin_amdgcn_readlane(__float_as_int(v), l));
}
__device__ __forceinline__ u32 aload(u32* p) {
    return __hip_atomic_load(p, __ATOMIC_ACQUIRE, WG);
}
// monotone score->bucket map (load balance only, never exactness)
__device__ __forceinline__ int bucket_of(float s) {
    float u = sqrtf(s);
    int b = (int)((u - 0.2236f) * 5275.0f);
    return min(max(b, 0), NB - 1);
}
// IoU(a,b) > 0.5  <=>  3*inter > areaA+areaB  (union>0: areas >= 1)
__device__ __forceinline__ bool iou_gt(float4 a, float aa, float4 b, float ab) {
    float iw = fmaxf(fminf(a.z, b.z) - fmaxf(a.x, b.x), 0.0f);
    float ih = fmaxf(fminf(a.w, b.w) - fmaxf(a.y, b.y), 0.0f);
    return 3.0f * (iw * ih) > aa + ab;
}

// ================= 1) prep: coalesced out init + cls transpose =================
#define INIT_BLKS 1641               // ceil(5000*84/256)
#define TR_BX     157
#define TR_BY     3
#define TR_BLKS   (TR_BX * TR_BY)

__global__ __launch_bounds__(256) void prep(const float* __restrict__ boxes,
                                            const float* __restrict__ cls,
                                            float* __restrict__ clsT,
                                            float* __restrict__ out) {
    __shared__ float tile[32][33];
    int b = blockIdx.x;
    if (b < INIT_BLKS) {
        int i = b * 256 + threadIdx.x;
        if (i < N_ANCHORS * OUT_COLS) {
            int row = i / OUT_COLS, col = i - row * OUT_COLS;
            out[i] = (col < 4) ? boxes[row * 4 + col] : 0.0f;
        }
        return;
    }
    b -= INIT_BLKS;
    int bx_ = b % TR_BX, by_ = b / TR_BX;
    int j0 = bx_ * 32, c0 = by_ * 32;
    int tx = threadIdx.x & 31, ty = threadIdx.x >> 5;
    #pragma unroll
    for (int r = 0; r < 32; r += 8) {
        int j = j0 + ty + r, c = c0 + tx;
        tile[ty + r][tx] = (j < N_ANCHORS && c < N_CLASSES) ? cls[j * N_CLASSES + c] : 0.0f;
    }
    __syncthreads();
    #pragma unroll
    for (int r = 0; r < 32; r += 8) {
        int c = c0 + ty + r, j = j0 + tx;
        if (c < N_CLASSES && j < N_ANCHORS) clsT[(size_t)c * N_ANCHORS + j] = tile[tx][ty + r];
    }
}

// ================= 2) per-class: LDS sort + pipelined all-LDS scan =================
// LDS carve: lk[5056]u64 @0 | hist[4096]u32 @40448 (aliased after sort:
//   Iring 8*64 u64 @40448 | Bring 8*64 float4 @44544 | kout 304 u64 @52736)
// | kbox 304 float4 @56832 | ctrl @61696
__global__ __launch_bounds__(BLOCK, 1) void nms(const float* __restrict__ clsT,
                                                const float4* __restrict__ boxes4,
                                                float* __restrict__ out) {
    __shared__ __align__(16) char SMEM[62080];
    u64*    lk     = (u64*)SMEM;
    u32*    hist   = (u32*)(SMEM + 40448);
    u64*    Iring  = (u64*)(SMEM + 40448);
    float4* Bring  = (float4*)(SMEM + 44544);
    u64*    kout   = (u64*)(SMEM + 52736);
    float4* kbox   = (float4*)(SMEM + 56832);
    u64*    KS     = (u64*)(SMEM + 61696);
    u64*    KSA    = (u64*)(SMEM + 61760);
    u32*    wtot   = (u32*)(SMEM + 61824);
    u32*    KBaA   = (u32*)(SMEM + 61888);
    u32*    KBa    = (u32*)(SMEM + 61920);
    u32*    flagI  = (u32*)(SMEM + 61952);
    u32*    flagK  = (u32*)(SMEM + 61984);
    u32*    flagKA = (u32*)(SMEM + 62016);
    u32*    prog   = (u32*)(SMEM + 62048);
    u32*    kcnt   = (u32*)(SMEM + 62052);

    const int c = blockIdx.x;
    const int t = threadIdx.x;
    const int lane = t & 63;
    const int wv = t >> 6;

    // ---------- sort phase (all 16 waves) ----------
    const float4* cp4 = (const float4*)(clsT + (size_t)c * N_ANCHORS);
    u32 sb[8];
    #pragma unroll
    for (int m = 0; m < 2; ++m) {
        int vi = m * 1024 + t;
        float4 v = make_float4(0.f, 0.f, 0.f, 0.f);
        if (vi < N_ANCHORS / 4) v = cp4[vi];
        sb[m * 4 + 0] = (v.x > SCORE_THR) ? __float_as_uint(v.x) : 0u;
        sb[m * 4 + 1] = (v.y > SCORE_THR) ? __float_as_uint(v.y) : 0u;
        sb[m * 4 + 2] = (v.z > SCORE_THR) ? __float_as_uint(v.z) : 0u;
        sb[m * 4 + 3] = (v.w > SCORE_THR) ? __float_as_uint(v.w) : 0u;
    }
    for (int b = t; b < NB; b += BLOCK) hist[b] = 0u;
    if (t < SLOTS) { flagI[t] = 0u; flagK[t] = 0u; flagKA[t] = 0u; }
    if (t == 0) { *prog = 0u; *kcnt = 0u; }
    __syncthreads();
    #pragma unroll
    for (int m = 0; m < 8; ++m)
        if (sb[m]) atomicAdd(&hist[bucket_of(__uint_as_float(sb[m]))], 1u);
    __syncthreads();

    const int hbase = t * 4;
    u32 vals[4]; u32 run = 0;
    #pragma unroll
    for (int k = 0; k < 4; ++k) { run += hist[hbase + k]; vals[k] = run; }
    u32 x = run;
    #pragma unroll
    for (int off = 1; off < 64; off <<= 1) { u32 y = __shfl_up(x, off); if (lane >= off) x += y; }
    if (lane == 63) wtot[wv] = x;
    __syncthreads();
    u32 woff = 0;
    for (int w = 0; w < wv; ++w) woff += wtot[w];
    const u32 exb = woff + x - run;
    #pragma unroll
    for (int k = 0; k < 4; ++k) hist[hbase + k] = exb + (k ? vals[k - 1] : 0u);
    __syncthreads();
    #pragma unroll
    for (int m = 0; m < 8; ++m) {
        if (sb[m]) {
            int j = ((m >> 2) * 1024 + t) * 4 + (m & 3);
            u32 pos = atomicAdd(&hist[bucket_of(__uint_as_float(sb[m]))], 1u);
            lk[pos] = ((u64)sb[m] << 32) | (u32)(~(u32)j);
        }
    }
    __syncthreads();
    const int total = (int)hist[NB - 1];
    for (int v = total + t; v < SORT_PAD; v += BLOCK) lk[v] = 0ull;
    for (int b = hbase; b < hbase + 4; ++b) {
        int s0 = b ? (int)hist[b - 1] : 0;
        int e  = (int)hist[b];
        for (int i = s0 + 1; i < e; ++i) {
            u64 key = lk[i]; int q = i - 1;
            while (q >= s0 && lk[q] < key) { lk[q + 1] = lk[q]; --q; }
            lk[q + 1] = key;
        }
    }
    __syncthreads();                    // LAST barrier; roles diverge
    const int nch = (total + 63) >> 6;

    if (wv >= 1 && wv <= 8) {
        // ======= intra workers (independent): full 64x64 IoU matrix =======
        for (int j = wv - 1; j < nch; j += 8) {
            const int slot = j & (SLOTS - 1);
            u32 p;
            for (;;) {
                p = aload(prog);
                if ((int)p >= j - (SLOTS - 1)) break;
                __builtin_amdgcn_s_sleep(2);
            }
            if (p >= DONEP) return;
            u64 e = lk[j * 64 + lane];
            u32 jj = e ? ~(u32)e : 0u;
            float4 bx = boxes4[jj];
            float ar = (bx.z - bx.x) * (bx.w - bx.y);
            u64 word = 0ull;
            #pragma unroll 16
            for (int q = 0; q < 64; ++q) {
                float4 o;
                o.x = readlane_f(bx.x, q); o.y = readlane_f(bx.y, q);
                o.z = readlane_f(bx.z, q); o.w = readlane_f(bx.w, q);
                float ao = (o.z - o.x) * (o.w - o.y);
                if (iou_gt(bx, ar, o, ao)) word |= (1ull << q);
            }
            Iring[slot * 64 + lane] = word;
            if (lane == 0)
                __hip_atomic_store(&flagI[slot], (u32)(j + 1), __ATOMIC_RELEASE, WG);
        }
        return;
    }
    if (wv >= 9 && wv <= 13) {
        // ======= stage-A sweeps: boxes -> Bring, kept-prefix suppression =======
        for (int j = wv - 9; j < nch; j += 5) {
            const int slot = j & (SLOTS - 1);
            u32 p;
            for (;;) {
                p = aload(prog);
                if ((int)p >= j - (SLOTS - 1)) break;
                __builtin_amdgcn_s_sleep(2);
            }
            if (p >= DONEP) return;
            u64 e = lk[j * 64 + lane];
            bool validL = (e != 0ull);
            u32 jj = validL ? ~(u32)e : 0u;
            float4 bx = boxes4[jj];
            float ar = (bx.z - bx.x) * (bx.w - bx.y);
            Bring[slot * 64 + lane] = bx;          // before flagKA release
            bool sup = !validL;
            u32 ka = aload(kcnt);
            u64 livem = __ballot(!sup);
            for (u32 r = 0; r < ka && livem; ++r) {
                float4 q = kbox[r];
                float aq = (q.z - q.x) * (q.w - q.y);
                if (!sup && iou_gt(bx, ar, q, aq)) sup = true;
                if ((r & 7u) == 7u) livem = __ballot(!sup);
            }
            u64 ksa = __ballot(sup);
            if (lane == 0) {
                KSA[slot] = ksa; KBaA[slot] = ka;
                __hip_atomic_store(&flagKA[slot], (u32)(j + 1), __ATOMIC_RELEASE, WG);
            }
        }
        return;
    }
    if (wv >= 14) {
        // ======= finishers: top-up recent keeps, publish KS =======
        for (int j = wv - 14; j < nch; j += 2) {
            const int slot = j & (SLOTS - 1);
            u32 p;
            for (;;) {
                p = aload(prog);
                if ((int)p >= j - 2) break;
                __builtin_amdgcn_s_sleep(1);
            }
            if (p >= DONEP) return;
            for (;;) {
                if (aload(&flagKA[slot]) == (u32)(j + 1)) break;
                if (aload(prog) >= DONEP) return;
                __builtin_amdgcn_s_sleep(1);
            }
            u32 ka = KBaA[slot];
            bool sup = (KSA[slot] >> lane) & 1ull;
            float4 bx = Bring[slot * 64 + lane];
            float ar = (bx.z - bx.x) * (bx.w - bx.y);
            u32 know = aload(kcnt);
            for (u32 r = ka; r < know; ++r) {
                float4 q = kbox[r];
                float aq = (q.z - q.x) * (q.w - q.y);
                if (!sup && iou_gt(bx, ar, q, aq)) sup = true;
            }
            u64 ks = __ballot(sup);
            if (lane == 0) {
                KS[slot] = ks; KBa[slot] = know;
                __hip_atomic_store(&flagK[slot], (u32)(j + 1), __ATOMIC_RELEASE, WG);
            }
        }
        return;
    }

    // ======= wave 0: serial scan — all-LDS steady state =======
    int kept = 0; u32 kcur = 0; bool capped = false;
    for (int k = 0; k < nch; ++k) {
        const int slot = k & (SLOTS - 1);
        u64 key = lk[k * 64 + lane];
        bool valid = (key != 0ull);
        u32 j = valid ? ~(u32)key : 0u;
        float sc = __uint_as_float((u32)(key >> 32));

        while (aload(&flagK[slot]) != (u32)(k + 1)) { }     // normally immediate
        u64 ks = KS[slot];
        if (ks != ~0ull) {
            u32 kb = KBa[slot];
            float4 bx = Bring[slot * 64 + lane];            // LDS, no global gather
            float ar = (bx.z - bx.x) * (bx.w - bx.y);
            bool alive = valid && !((ks >> lane) & 1ull);
            for (u32 r = kb; r < kcur; ++r) {               // ~last-2-chunks keeps
                float4 q = kbox[r];
                float aq = (q.z - q.x) * (q.w - q.y);
                if (alive && iou_gt(bx, ar, q, aq)) alive = false;
            }
            u64 rem = __ballot(alive);
            if (rem) {
                while (aload(&flagI[slot]) != (u32)(k + 1)) { }
                u64 I = Iring[slot * 64 + lane];
                u64 km = 0ull;
                while (rem) {                               // SALU keep chain
                    int pos = __ffsll((long long)rem) - 1;
                    km |= 1ull << pos;
                    if (++kept == MAX_BOXES) { capped = true; break; }
                    u32 lo = (u32)__builtin_amdgcn_readlane((int)(u32)I, pos);
                    u32 hi = (u32)__builtin_amdgcn_readlane((int)(u32)(I >> 32), pos);
                    rem &= ~(((u64)hi << 32) | (u64)lo);    // diag bit kills pos
                }
                if ((km >> lane) & 1ull) {
                    int rank = (int)__popcll(km & ((1ull << lane) - 1ull));
                    kbox[kcur + rank] = bx;
                    kout[kcur + rank] = ((u64)__float_as_uint(sc) << 32) | j;
                }
                kcur += (u32)__popcll(km);
            }
        }
        if (capped) break;
        if (lane == 0) {
            __hip_atomic_store(kcnt, kcur, __ATOMIC_RELEASE, WG);
            __hip_atomic_store(prog, (u32)(k + 1), __ATOMIC_RELEASE, WG);
        }
    }
    if (lane == 0) __hip_atomic_store(prog, (u32)DONEP, __ATOMIC_RELEASE, WG);

    // flush buffered keeps to global (off the serial chain)
    for (u32 i = (u32)lane; i < kcur; i += 64) {
        u64 e = kout[i];
        out[(size_t)((u32)e) * OUT_COLS + 4 + c] = __uint_as_float((u32)(e >> 32));
    }
}

extern "C" void kernel_launch(void* const* d_in, const int* in_sizes, int n_in,
                              void* d_out, int out_size, void* d_ws, size_t ws_size,
                              hipStream_t stream) {
    const float* boxes = (const float*)d_in[0];
    const float* cls   = (const float*)d_in[1];
    float* out = (float*)d_out;
    float* clsT = (float*)d_ws;                    // 1.60 MB scratch

    prep<<<INIT_BLKS + TR_BLKS, 256, 0, stream>>>(boxes, cls, clsT, out);
    nms<<<N_CLASSES, BLOCK, 0, stream>>>(clsT, (const float4*)boxes, out);
}

// Round 13
// 141.958 us; speedup vs baseline: 1.4924x; 1.4794x over previous
//
#include <hip/hip_runtime.h>

#define N_ANCHORS 5000
#define N_CLASSES 80
#define OUT_COLS  84
#define MAX_BOXES 300
#define SCORE_THR 0.05f

#define SORT_PAD  5056
#define NB        4096
#define BLOCK     1024
#define SLOTS     8
#define DONEP     0x40000000

typedef unsigned long long u64;
typedef unsigned int u32;

#define WG __HIP_MEMORY_SCOPE_WORKGROUP

__device__ __forceinline__ float readlane_f(float v, int l) {
    return __int_as_float(__builtin_amdgcn_readlane(__float_as_int(v), l));
}
__device__ __forceinline__ u32 aload(u32* p) {
    return __hip_atomic_load(p, __ATOMIC_ACQUIRE, WG);
}
// monotone score->bucket map (load balance only, never exactness)
__device__ __forceinline__ int bucket_of(float s) {
    float u = sqrtf(s);
    int b = (int)((u - 0.2236f) * 5275.0f);
    return min(max(b, 0), NB - 1);
}
// IoU(me,q) > 0.5  <=>  3*inter > areaMe+areaQ ; sentinel q (1e9^4) -> always false
__device__ __forceinline__ bool iou_q(float4 a, float aa, float4 q) {
    float iw = fmaxf(fminf(a.z, q.z) - fmaxf(a.x, q.x), 0.0f);
    float ih = fmaxf(fminf(a.w, q.w) - fmaxf(a.y, q.y), 0.0f);
    float aq = (q.z - q.x) * (q.w - q.y);
    return 3.0f * (iw * ih) > aa + aq;
}

// ================= 1) prep: coalesced out init + cls transpose =================
#define INIT_BLKS 1641
#define TR_BX     157
#define TR_BY     3
#define TR_BLKS   (TR_BX * TR_BY)

__global__ __launch_bounds__(256) void prep(const float* __restrict__ boxes,
                                            const float* __restrict__ cls,
                                            float* __restrict__ clsT,
                                            float* __restrict__ out) {
    __shared__ float tile[32][33];
    int b = blockIdx.x;
    if (b < INIT_BLKS) {
        int i = b * 256 + threadIdx.x;
        if (i < N_ANCHORS * OUT_COLS) {
            int row = i / OUT_COLS, col = i - row * OUT_COLS;
            out[i] = (col < 4) ? boxes[row * 4 + col] : 0.0f;
        }
        return;
    }
    b -= INIT_BLKS;
    int bx_ = b % TR_BX, by_ = b / TR_BX;
    int j0 = bx_ * 32, c0 = by_ * 32;
    int tx = threadIdx.x & 31, ty = threadIdx.x >> 5;
    #pragma unroll
    for (int r = 0; r < 32; r += 8) {
        int j = j0 + ty + r, c = c0 + tx;
        tile[ty + r][tx] = (j < N_ANCHORS && c < N_CLASSES) ? cls[j * N_CLASSES + c] : 0.0f;
    }
    __syncthreads();
    #pragma unroll
    for (int r = 0; r < 32; r += 8) {
        int c = c0 + ty + r, j = j0 + tx;
        if (c < N_CLASSES && j < N_ANCHORS) clsT[(size_t)c * N_ANCHORS + j] = tile[tx][ty + r];
    }
}

// ================= 2) per-class: LDS sort + pipelined scan =================
// LDS: lk[5056]u64 @0 | hist[4096]u32 @40448 (post-sort aliased:
//   Iring 8*64 u64 @40448 | Bring 8*64 f4 @44544 | kout 304 u64 @52736)
// | kbox 308 f4 @56832 | KS @61760 | wtot @61824 | KBa @61888
// | flagI @61920 | flagK @61952 | prog @61984 | kcnt @61988
__global__ __launch_bounds__(BLOCK, 1) void nms(const float* __restrict__ clsT,
                                                const float4* __restrict__ boxes4,
                                                float* __restrict__ out) {
    __shared__ __align__(16) char SMEM[62016];
    u64*    lk    = (u64*)SMEM;
    u32*    hist  = (u32*)(SMEM + 40448);
    u64*    Iring = (u64*)(SMEM + 40448);
    float4* Bring = (float4*)(SMEM + 44544);
    u64*    kout  = (u64*)(SMEM + 52736);
    float4* kbox  = (float4*)(SMEM + 56832);
    u64*    KS    = (u64*)(SMEM + 61760);
    u32*    wtot  = (u32*)(SMEM + 61824);
    u32*    KBa   = (u32*)(SMEM + 61888);
    u32*    flagI = (u32*)(SMEM + 61920);
    u32*    flagK = (u32*)(SMEM + 61952);
    u32*    prog  = (u32*)(SMEM + 61984);
    u32*    kcnt  = (u32*)(SMEM + 61988);

    const int c = blockIdx.x;
    const int t = threadIdx.x;
    const int lane = t & 63;
    const int wv = t >> 6;

    // ---------- sort phase (all 16 waves) ----------
    const float4* cp4 = (const float4*)(clsT + (size_t)c * N_ANCHORS);
    u32 sb[8];
    #pragma unroll
    for (int m = 0; m < 2; ++m) {
        int vi = m * 1024 + t;
        float4 v = make_float4(0.f, 0.f, 0.f, 0.f);
        if (vi < N_ANCHORS / 4) v = cp4[vi];
        sb[m * 4 + 0] = (v.x > SCORE_THR) ? __float_as_uint(v.x) : 0u;
        sb[m * 4 + 1] = (v.y > SCORE_THR) ? __float_as_uint(v.y) : 0u;
        sb[m * 4 + 2] = (v.z > SCORE_THR) ? __float_as_uint(v.z) : 0u;
        sb[m * 4 + 3] = (v.w > SCORE_THR) ? __float_as_uint(v.w) : 0u;
    }
    for (int b = t; b < NB; b += BLOCK) hist[b] = 0u;
    if (t < 308) kbox[t] = make_float4(1e9f, 1e9f, 1e9f, 1e9f);   // sentinels
    if (t < SLOTS) { flagI[t] = 0u; flagK[t] = 0u; }
    if (t == 0) { *prog = 0u; *kcnt = 0u; }
    __syncthreads();
    #pragma unroll
    for (int m = 0; m < 8; ++m)
        if (sb[m]) atomicAdd(&hist[bucket_of(__uint_as_float(sb[m]))], 1u);
    __syncthreads();

    const int hbase = t * 4;
    u32 vals[4]; u32 run = 0;
    #pragma unroll
    for (int k = 0; k < 4; ++k) { run += hist[hbase + k]; vals[k] = run; }
    u32 x = run;
    #pragma unroll
    for (int off = 1; off < 64; off <<= 1) { u32 y = __shfl_up(x, off); if (lane >= off) x += y; }
    if (lane == 63) wtot[wv] = x;
    __syncthreads();
    u32 woff = 0;
    for (int w = 0; w < wv; ++w) woff += wtot[w];
    const u32 exb = woff + x - run;
    #pragma unroll
    for (int k = 0; k < 4; ++k) hist[hbase + k] = exb + (k ? vals[k - 1] : 0u);
    __syncthreads();
    #pragma unroll
    for (int m = 0; m < 8; ++m) {
        if (sb[m]) {
            int j = ((m >> 2) * 1024 + t) * 4 + (m & 3);
            u32 pos = atomicAdd(&hist[bucket_of(__uint_as_float(sb[m]))], 1u);
            lk[pos] = ((u64)sb[m] << 32) | (u32)(~(u32)j);
        }
    }
    __syncthreads();
    const int total = (int)hist[NB - 1];
    for (int v = total + t; v < SORT_PAD; v += BLOCK) lk[v] = 0ull;
    for (int b = hbase; b < hbase + 4; ++b) {
        int s0 = b ? (int)hist[b - 1] : 0;
        int e  = (int)hist[b];
        for (int i = s0 + 1; i < e; ++i) {
            u64 key = lk[i]; int q = i - 1;
            while (q >= s0 && lk[q] < key) { lk[q + 1] = lk[q]; --q; }
            lk[q + 1] = key;
        }
    }
    __syncthreads();                    // LAST barrier; roles diverge
    const int nch = (total + 63) >> 6;

    if (wv >= 1 && wv <= 4) {
        // ======= intra workers: full 64x64 IoU matrix (independent) =======
        for (int j = wv - 1; j < nch; j += 4) {
            const int slot = j & (SLOTS - 1);
            u64 e = lk[j * 64 + lane];
            u32 jj = e ? ~(u32)e : 0u;
            float4 bx = boxes4[jj];                      // issued before gate
            float ar = (bx.z - bx.x) * (bx.w - bx.y);
            u32 p;
            for (;;) {
                p = aload(prog);
                if ((int)p >= j - (SLOTS - 1)) break;
                __builtin_amdgcn_s_sleep(2);
            }
            if (p >= DONEP) return;
            u64 word = 0ull;
            #pragma unroll 16
            for (int q = 0; q < 64; ++q) {
                float4 o;
                o.x = readlane_f(bx.x, q); o.y = readlane_f(bx.y, q);
                o.z = readlane_f(bx.z, q); o.w = readlane_f(bx.w, q);
                if (iou_q(bx, ar, o)) word |= (1ull << q);
            }
            Iring[slot * 64 + lane] = word;
            if (lane == 0)
                __hip_atomic_store(&flagI[slot], (u32)(j + 1), __ATOMIC_RELEASE, WG);
        }
        return;
    }
    if (wv >= 5) {
        // ======= fused sweeps: 8-group kept-prefix, then top-up + publish =======
        for (int j = wv - 5; j < nch; j += 11) {
            const int slot = j & (SLOTS - 1);
            u64 e = lk[j * 64 + lane];
            bool validL = (e != 0ull);
            u32 jj = validL ? ~(u32)e : 0u;
            float4 bx = boxes4[jj];                      // issued before gate
            float ar = (bx.z - bx.x) * (bx.w - bx.y);
            u32 p;
            for (;;) {                                   // slot-free gate
                p = aload(prog);
                if ((int)p >= j - (SLOTS - 1)) break;
                __builtin_amdgcn_s_sleep(2);
            }
            if (p >= DONEP) return;
            Bring[slot * 64 + lane] = bx;
            bool sup = !validL;
            u32 ka = aload(kcnt);
            u32 kaR = (ka + 7) & ~7u;                    // sentinel-padded
            for (u32 r = 0; r < kaR; r += 8) {
                float4 q0 = kbox[r + 0], q1 = kbox[r + 1], q2 = kbox[r + 2], q3 = kbox[r + 3];
                float4 q4 = kbox[r + 4], q5 = kbox[r + 5], q6 = kbox[r + 6], q7 = kbox[r + 7];
                bool s = iou_q(bx, ar, q0) | iou_q(bx, ar, q1) | iou_q(bx, ar, q2) | iou_q(bx, ar, q3)
                       | iou_q(bx, ar, q4) | iou_q(bx, ar, q5) | iou_q(bx, ar, q6) | iou_q(bx, ar, q7);
                sup = sup || s;
                if (__ballot(!sup) == 0ull) break;       // whole chunk dead
            }
            for (;;) {                                   // stage-B gate
                p = aload(prog);
                if ((int)p >= j - 2) break;
                __builtin_amdgcn_s_sleep(1);
            }
            u32 kb2 = (p >= DONEP) ? ka : aload(kcnt);
            if (kb2 < ka) kb2 = ka;
            u32 r1 = (kb2 + 3) & ~3u;
            for (u32 r = ka & ~3u; r < r1; r += 4) {     // overlap retests harmless
                float4 q0 = kbox[r + 0], q1 = kbox[r + 1], q2 = kbox[r + 2], q3 = kbox[r + 3];
                bool s = iou_q(bx, ar, q0) | iou_q(bx, ar, q1) | iou_q(bx, ar, q2) | iou_q(bx, ar, q3);
                sup = sup || s;
            }
            u64 ks = __ballot(sup);
            if (lane == 0) {
                KS[slot] = ks; KBa[slot] = kb2;
                __hip_atomic_store(&flagK[slot], (u32)(j + 1), __ATOMIC_RELEASE, WG);
            }
            if (p >= DONEP) return;
        }
        return;
    }

    // ======= wave 0: serial scan (all-LDS steady state) =======
    int kept = 0; u32 kcur = 0; bool capped = false;
    for (int k = 0; k < nch; ++k) {
        const int slot = k & (SLOTS - 1);
        u64 key = lk[k * 64 + lane];
        bool valid = (key != 0ull);
        u32 j = valid ? ~(u32)key : 0u;
        float sc = __uint_as_float((u32)(key >> 32));

        while (aload(&flagK[slot]) != (u32)(k + 1)) { }   // normally immediate
        u64 ks = KS[slot];
        if (ks != ~0ull) {
            u32 kb = KBa[slot];
            float4 bx = Bring[slot * 64 + lane];
            float ar = (bx.z - bx.x) * (bx.w - bx.y);
            bool alive = valid && !((ks >> lane) & 1ull);
            u32 r1 = (kcur + 3) & ~3u;                    // top-up recent keeps
            for (u32 r = kb & ~3u; r < r1; r += 4) {
                float4 q0 = kbox[r + 0], q1 = kbox[r + 1], q2 = kbox[r + 2], q3 = kbox[r + 3];
                bool s = iou_q(bx, ar, q0) | iou_q(bx, ar, q1) | iou_q(bx, ar, q2) | iou_q(bx, ar, q3);
                alive = alive && !s;
            }
            u64 rem = __ballot(alive);
            if (rem) {
                while (aload(&flagI[slot]) != (u32)(k + 1)) { }
                u64 I = Iring[slot * 64 + lane];
                u64 km = 0ull;
                while (rem) {                             // SALU keep chain
                    int pos = __ffsll((long long)rem) - 1;
                    km |= 1ull << pos;
                    if (++kept == MAX_BOXES) { capped = true; break; }
                    u32 lo = (u32)__builtin_amdgcn_readlane((int)(u32)I, pos);
                    u32 hi = (u32)__builtin_amdgcn_readlane((int)(u32)(I >> 32), pos);
                    rem &= ~(((u64)hi << 32) | (u64)lo);  // diag bit kills pos
                }
                if ((km >> lane) & 1ull) {
                    int rank = (int)__popcll(km & ((1ull << lane) - 1ull));
                    kbox[kcur + rank] = bx;
                    kout[kcur + rank] = ((u64)__float_as_uint(sc) << 32) | j;
                }
                kcur += (u32)__popcll(km);
            }
        }
        if (capped) break;
        if (lane == 0) {
            __hip_atomic_store(kcnt, kcur, __ATOMIC_RELEASE, WG);
            __hip_atomic_store(prog, (u32)(k + 1), __ATOMIC_RELEASE, WG);
        }
    }
    if (lane == 0) __hip_atomic_store(prog, (u32)DONEP, __ATOMIC_RELEASE, WG);

    // flush buffered keeps to global (off the serial chain)
    for (u32 i = (u32)lane; i < kcur; i += 64) {
        u64 e = kout[i];
        out[(size_t)((u32)e) * OUT_COLS + 4 + c] = __uint_as_float((u32)(e >> 32));
    }
}

extern "C" void kernel_launch(void* const* d_in, const int* in_sizes, int n_in,
                              void* d_out, int out_size, void* d_ws, size_t ws_size,
                              hipStream_t stream) {
    const float* boxes = (const float*)d_in[0];
    const float* cls   = (const float*)d_in[1];
    float* out = (float*)d_out;
    float* clsT = (float*)d_ws;                    // 1.60 MB scratch

    prep<<<INIT_BLKS + TR_BLKS, 256, 0, stream>>>(boxes, cls, clsT, out);
    nms<<<N_CLASSES, BLOCK, 0, stream>>>(clsT, (const float4*)boxes, out);
}

// Round 14
// 139.940 us; speedup vs baseline: 1.5139x; 1.0144x over previous
//
#include <hip/hip_runtime.h>

#define N_ANCHORS 5000
#define N_CLASSES 80
#define OUT_COLS  84
#define MAX_BOXES 300
#define SCORE_THR 0.05f

#define SORT_PAD  5056
#define NB        4096
#define BLOCK     1024
#define SLOTS     8
#define DONEP     0x40000000

typedef unsigned long long u64;
typedef unsigned int u32;

#define WG __HIP_MEMORY_SCOPE_WORKGROUP

__device__ __forceinline__ float readlane_f(float v, int l) {
    return __int_as_float(__builtin_amdgcn_readlane(__float_as_int(v), l));
}
__device__ __forceinline__ u32 aload(u32* p) {
    return __hip_atomic_load(p, __ATOMIC_ACQUIRE, WG);
}
// monotone score->bucket map (load balance only, never exactness)
__device__ __forceinline__ int bucket_of(float s) {
    float u = sqrtf(s);
    int b = (int)((u - 0.2236f) * 5275.0f);
    return min(max(b, 0), NB - 1);
}
// IoU(me,q) > 0.5  <=>  3*inter > areaMe+areaQ ; sentinel q (1e9) -> always false
__device__ __forceinline__ bool iou_q(float4 a, float aa, float4 q) {
    float iw = fmaxf(fminf(a.z, q.z) - fmaxf(a.x, q.x), 0.0f);
    float ih = fmaxf(fminf(a.w, q.w) - fmaxf(a.y, q.y), 0.0f);
    float aq = (q.z - q.x) * (q.w - q.y);
    return 3.0f * (iw * ih) > aa + aq;
}

// ================= 1) prep: coalesced out init + cls transpose =================
#define INIT_BLKS 1641
#define TR_BX     157
#define TR_BY     3
#define TR_BLKS   (TR_BX * TR_BY)

__global__ __launch_bounds__(256) void prep(const float* __restrict__ boxes,
                                            const float* __restrict__ cls,
                                            float* __restrict__ clsT,
                                            float* __restrict__ out) {
    __shared__ float tile[32][33];
    int b = blockIdx.x;
    if (b < INIT_BLKS) {
        int i = b * 256 + threadIdx.x;
        if (i < N_ANCHORS * OUT_COLS) {
            int row = i / OUT_COLS, col = i - row * OUT_COLS;
            out[i] = (col < 4) ? boxes[row * 4 + col] : 0.0f;
        }
        return;
    }
    b -= INIT_BLKS;
    int bx_ = b % TR_BX, by_ = b / TR_BX;
    int j0 = bx_ * 32, c0 = by_ * 32;
    int tx = threadIdx.x & 31, ty = threadIdx.x >> 5;
    #pragma unroll
    for (int r = 0; r < 32; r += 8) {
        int j = j0 + ty + r, c = c0 + tx;
        tile[ty + r][tx] = (j < N_ANCHORS && c < N_CLASSES) ? cls[j * N_CLASSES + c] : 0.0f;
    }
    __syncthreads();
    #pragma unroll
    for (int r = 0; r < 32; r += 8) {
        int c = c0 + ty + r, j = j0 + tx;
        if (c < N_CLASSES && j < N_ANCHORS) clsT[(size_t)c * N_ANCHORS + j] = tile[tx][ty + r];
    }
}

// ================= 2) per-class: LDS sort + pipelined scan =================
// LDS: lk[5056]u64 @0 | hist[4096]u32 @40448 (post-sort aliased:
//   Iring 8*64 u64 @40448 | Bring 8*64 f4 @44544 | kout 304 u64 @52736)
// | kbox 320 f4 @56832 | KS @61952 | wtot @62016 | KBa @62080
// | flagI @62112 | flagK @62144 | prog @62176 | kcnt @62180
__global__ __launch_bounds__(BLOCK, 1) void nms(const float* __restrict__ clsT,
                                                const float4* __restrict__ boxes4,
                                                float* __restrict__ out) {
    __shared__ __align__(16) char SMEM[62208];
    u64*    lk    = (u64*)SMEM;
    u32*    hist  = (u32*)(SMEM + 40448);
    u64*    Iring = (u64*)(SMEM + 40448);
    float4* Bring = (float4*)(SMEM + 44544);
    u64*    kout  = (u64*)(SMEM + 52736);
    float4* kbox  = (float4*)(SMEM + 56832);   // 320 slots, sentinel-padded
    u64*    KS    = (u64*)(SMEM + 61952);
    u32*    wtot  = (u32*)(SMEM + 62016);
    u32*    KBa   = (u32*)(SMEM + 62080);
    u32*    flagI = (u32*)(SMEM + 62112);
    u32*    flagK = (u32*)(SMEM + 62144);
    u32*    prog  = (u32*)(SMEM + 62176);
    u32*    kcnt  = (u32*)(SMEM + 62180);

    const int c = blockIdx.x;
    const int t = threadIdx.x;
    const int lane = t & 63;
    const int wv = t >> 6;

    // ---------- sort phase (all 16 waves) ----------
    const float4* cp4 = (const float4*)(clsT + (size_t)c * N_ANCHORS);
    u32 sb[8];
    #pragma unroll
    for (int m = 0; m < 2; ++m) {
        int vi = m * 1024 + t;
        float4 v = make_float4(0.f, 0.f, 0.f, 0.f);
        if (vi < N_ANCHORS / 4) v = cp4[vi];
        sb[m * 4 + 0] = (v.x > SCORE_THR) ? __float_as_uint(v.x) : 0u;
        sb[m * 4 + 1] = (v.y > SCORE_THR) ? __float_as_uint(v.y) : 0u;
        sb[m * 4 + 2] = (v.z > SCORE_THR) ? __float_as_uint(v.z) : 0u;
        sb[m * 4 + 3] = (v.w > SCORE_THR) ? __float_as_uint(v.w) : 0u;
    }
    for (int b = t; b < NB; b += BLOCK) hist[b] = 0u;
    if (t < 320) kbox[t] = make_float4(1e9f, 1e9f, 1e9f, 1e9f);   // sentinels
    if (t < SLOTS) { flagI[t] = 0u; flagK[t] = 0u; }
    if (t == 0) { *prog = 0u; *kcnt = 0u; }
    __syncthreads();
    #pragma unroll
    for (int m = 0; m < 8; ++m)
        if (sb[m]) atomicAdd(&hist[bucket_of(__uint_as_float(sb[m]))], 1u);
    __syncthreads();

    const int hbase = t * 4;
    u32 vals[4]; u32 run = 0;
    #pragma unroll
    for (int k = 0; k < 4; ++k) { run += hist[hbase + k]; vals[k] = run; }
    u32 x = run;
    #pragma unroll
    for (int off = 1; off < 64; off <<= 1) { u32 y = __shfl_up(x, off); if (lane >= off) x += y; }
    if (lane == 63) wtot[wv] = x;
    __syncthreads();
    u32 woff = 0;
    for (int w = 0; w < wv; ++w) woff += wtot[w];
    const u32 exb = woff + x - run;
    #pragma unroll
    for (int k = 0; k < 4; ++k) hist[hbase + k] = exb + (k ? vals[k - 1] : 0u);
    __syncthreads();
    #pragma unroll
    for (int m = 0; m < 8; ++m) {
        if (sb[m]) {
            int j = ((m >> 2) * 1024 + t) * 4 + (m & 3);
            u32 pos = atomicAdd(&hist[bucket_of(__uint_as_float(sb[m]))], 1u);
            lk[pos] = ((u64)sb[m] << 32) | (u32)(~(u32)j);
        }
    }
    __syncthreads();
    const int total = (int)hist[NB - 1];
    for (int v = total + t; v < SORT_PAD; v += BLOCK) lk[v] = 0ull;
    for (int b = hbase; b < hbase + 4; ++b) {
        int s0 = b ? (int)hist[b - 1] : 0;
        int e  = (int)hist[b];
        for (int i = s0 + 1; i < e; ++i) {
            u64 key = lk[i]; int q = i - 1;
            while (q >= s0 && lk[q] < key) { lk[q + 1] = lk[q]; --q; }
            lk[q + 1] = key;
        }
    }
    __syncthreads();                    // LAST barrier; roles diverge
    const int nch = (total + 63) >> 6;

    if (wv >= 1 && wv <= 4) {
        // ======= intra workers: full 64x64 IoU matrix (independent) =======
        for (int j = wv - 1; j < nch; j += 4) {
            const int slot = j & (SLOTS - 1);
            u64 e = lk[j * 64 + lane];
            u32 jj = e ? ~(u32)e : 0u;
            float4 bx = boxes4[jj];                      // issued before gate
            float ar = (bx.z - bx.x) * (bx.w - bx.y);
            u32 p;
            for (;;) {
                p = aload(prog);
                if ((int)p >= j - (SLOTS - 1)) break;
                __builtin_amdgcn_s_sleep(2);
            }
            if (p >= DONEP) return;
            u64 word = 0ull;
            #pragma unroll 16
            for (int q = 0; q < 64; ++q) {
                float4 o;
                o.x = readlane_f(bx.x, q); o.y = readlane_f(bx.y, q);
                o.z = readlane_f(bx.z, q); o.w = readlane_f(bx.w, q);
                if (iou_q(bx, ar, o)) word |= (1ull << q);
            }
            Iring[slot * 64 + lane] = word;
            if (lane == 0)
                __hip_atomic_store(&flagI[slot], (u32)(j + 1), __ATOMIC_RELEASE, WG);
        }
        return;
    }
    if (wv >= 5) {
        // ======= sweeps: lane-parallel-kept, candidate-broadcast =======
        for (int j = wv - 5; j < nch; j += 11) {
            const int slot = j & (SLOTS - 1);
            u64 e = lk[j * 64 + lane];
            bool validL = (e != 0ull);
            u32 jj = validL ? ~(u32)e : 0u;
            float4 bx = boxes4[jj];                      // issued before gate
            float ar = (bx.z - bx.x) * (bx.w - bx.y);
            u32 p;
            for (;;) {                                   // slot-free gate
                p = aload(prog);
                if ((int)p >= j - (SLOTS - 1)) break;
                __builtin_amdgcn_s_sleep(2);
            }
            if (p >= DONEP) return;
            Bring[slot * 64 + lane] = bx;
            u64 vm = __ballot(validL);
            u64 ks = ~vm;                                // invalid = suppressed
            u32 ka = aload(kcnt);
            const int ng = (int)((ka + 63) >> 6);        // 0..5 kept groups

            if (ka) {
                // register copy of kept list: lane holds kept g*64+lane
                float4 kb[5];
                #pragma unroll
                for (int g = 0; g < 5; ++g)
                    kb[g] = (g < ng) ? kbox[g * 64 + lane]
                                     : make_float4(1e9f, 1e9f, 1e9f, 1e9f);
                for (int i = 0; i < 64; ++i) {
                    if (!((vm >> i) & 1ull)) continue;   // uniform skip
                    float cx1 = readlane_f(bx.x, i), cy1 = readlane_f(bx.y, i);
                    float cx2 = readlane_f(bx.z, i), cy2 = readlane_f(bx.w, i);
                    float car = (cx2 - cx1) * (cy2 - cy1);
                    bool found = false;
                    #pragma unroll
                    for (int g = 0; g < 5; ++g) {
                        if (!found && g < ng) {          // uniform guard: real skip
                            float iw = fmaxf(fminf(cx2, kb[g].z) - fmaxf(cx1, kb[g].x), 0.0f);
                            float ih = fmaxf(fminf(cy2, kb[g].w) - fmaxf(cy1, kb[g].y), 0.0f);
                            float aq = (kb[g].z - kb[g].x) * (kb[g].w - kb[g].y);
                            bool s = 3.0f * (iw * ih) > car + aq;
                            found = (__ballot(s) != 0ull);
                        }
                    }
                    if (found) ks |= (1ull << i);
                }
            }
            bool sup = (ks >> lane) & 1ull;

            for (;;) {                                   // stage-B gate
                p = aload(prog);
                if ((int)p >= j - 2) break;
                __builtin_amdgcn_s_sleep(1);
            }
            u32 kb2 = (p >= DONEP) ? ka : aload(kcnt);
            if (kb2 < ka) kb2 = ka;
            u32 r1 = (kb2 + 3) & ~3u;                    // top-up: recent keeps (few)
            for (u32 r = ka & ~3u; r < r1; r += 4) {
                float4 q0 = kbox[r + 0], q1 = kbox[r + 1], q2 = kbox[r + 2], q3 = kbox[r + 3];
                bool s = iou_q(bx, ar, q0) | iou_q(bx, ar, q1) | iou_q(bx, ar, q2) | iou_q(bx, ar, q3);
                sup = sup || s;
            }
            u64 ksf = __ballot(sup);
            if (lane == 0) {
                KS[slot] = ksf; KBa[slot] = kb2;
                __hip_atomic_store(&flagK[slot], (u32)(j + 1), __ATOMIC_RELEASE, WG);
            }
            if (p >= DONEP) return;
        }
        return;
    }

    // ======= wave 0: serial scan (all-LDS steady state) =======
    int kept = 0; u32 kcur = 0; bool capped = false;
    for (int k = 0; k < nch; ++k) {
        const int slot = k & (SLOTS - 1);
        u64 key = lk[k * 64 + lane];
        bool valid = (key != 0ull);
        u32 j = valid ? ~(u32)key : 0u;
        float sc = __uint_as_float((u32)(key >> 32));

        while (aload(&flagK[slot]) != (u32)(k + 1)) { }   // normally immediate
        u64 ks = KS[slot];
        if (ks != ~0ull) {
            u32 kb = KBa[slot];
            float4 bx = Bring[slot * 64 + lane];
            float ar = (bx.z - bx.x) * (bx.w - bx.y);
            bool alive = valid && !((ks >> lane) & 1ull);
            u32 r1 = (kcur + 3) & ~3u;                    // top-up recent keeps
            for (u32 r = kb & ~3u; r < r1; r += 4) {
                float4 q0 = kbox[r + 0], q1 = kbox[r + 1], q2 = kbox[r + 2], q3 = kbox[r + 3];
                bool s = iou_q(bx, ar, q0) | iou_q(bx, ar, q1) | iou_q(bx, ar, q2) | iou_q(bx, ar, q3);
                alive = alive && !s;
            }
            u64 rem = __ballot(alive);
            if (rem) {
                while (aload(&flagI[slot]) != (u32)(k + 1)) { }
                u64 I = Iring[slot * 64 + lane];
                u64 km = 0ull;
                while (rem) {                             // SALU keep chain
                    int pos = __ffsll((long long)rem) - 1;
                    km |= 1ull << pos;
                    if (++kept == MAX_BOXES) { capped = true; break; }
                    u32 lo = (u32)__builtin_amdgcn_readlane((int)(u32)I, pos);
                    u32 hi = (u32)__builtin_amdgcn_readlane((int)(u32)(I >> 32), pos);
                    rem &= ~(((u64)hi << 32) | (u64)lo);  // diag bit kills pos
                }
                if ((km >> lane) & 1ull) {
                    int rank = (int)__popcll(km & ((1ull << lane) - 1ull));
                    kbox[kcur + rank] = bx;
                    kout[kcur + rank] = ((u64)__float_as_uint(sc) << 32) | j;
                }
                kcur += (u32)__popcll(km);
            }
        }
        if (capped) break;
        if (lane == 0) {
            __hip_atomic_store(kcnt, kcur, __ATOMIC_RELEASE, WG);
            __hip_atomic_store(prog, (u32)(k + 1), __ATOMIC_RELEASE, WG);
        }
    }
    if (lane == 0) __hip_atomic_store(prog, (u32)DONEP, __ATOMIC_RELEASE, WG);

    // flush buffered keeps to global (off the serial chain)
    for (u32 i = (u32)lane; i < kcur; i += 64) {
        u64 e = kout[i];
        out[(size_t)((u32)e) * OUT_COLS + 4 + c] = __uint_as_float((u32)(e >> 32));
    }
}

extern "C" void kernel_launch(void* const* d_in, const int* in_sizes, int n_in,
                              void* d_out, int out_size, void* d_ws, size_t ws_size,
                              hipStream_t stream) {
    const float* boxes = (const float*)d_in[0];
    const float* cls   = (const float*)d_in[1];
    float* out = (float*)d_out;
    float* clsT = (float*)d_ws;                    // 1.60 MB scratch

    prep<<<INIT_BLKS + TR_BLKS, 256, 0, stream>>>(boxes, cls, clsT, out);
    nms<<<N_CLASSES, BLOCK, 0, stream>>>(clsT, (const float4*)boxes, out);
}